// Round 3
// baseline (166.126 us; speedup 1.0000x reference)
//
#include <hip/hip_runtime.h>

// LstmSequential round 15: full-M tiles — stop paying MFMA for dead rows.
// r14 post-mortem: per SIMD-step budget (2682 cyc) = ~930 MFMA + ~450 VALU +
// ~450 trans + idle. Half the MFMA is waste: 16x16 tiles carried only 8 live
// batch rows (tile-rows {4q,4q+1}). This round: 16 live rows per block,
// 256 blocks x 4 waves (1 block/CU, 1 wave/SIMD). Per-SIMD MFMA halves
// (930->465 cyc/step); epi/trans per SIMD unchanged (4 rows/SIMD either way).
// Cost: 1 wave/SIMD exposes ds_read latency (~150 cyc/step) — much smaller
// than the MFMA savings. All else unchanged from r14: cross-step pipelining
// (layer 2 one step behind), lgkm-only end-of-step barrier, rational epilogue
// (5 exp2 + 2 rcp, NSC pre-scaled weights), depth-2 E1 prefetch, MFMA prep.
//
// A-buffer (2 bufs, p=t&1): fp16 A-matrix [16 m x 128 k] in fragment layout,
//   f16 index of (m,k) = ((k>>3)*16 + m)*8 + (k&7); lane's kt-frag = uint4
//   [kt*64+lane]. k 0..63 = h1, k 64..127 = h2. All 16 m-rows now live:
//   tile-row m = 4q+r (q=lane>>4, r=0..3) <-> batch row row0 + 4q + r.

#define VOCAB 10000
#define EMB   100
#define SEQ   80
#define BATCH 4096
#define NGRID 256

typedef _Float16 f16;
typedef _Float16 f16x8 __attribute__((ext_vector_type(8)));
typedef _Float16 half2_t __attribute__((ext_vector_type(2)));
typedef float    f32x4 __attribute__((ext_vector_type(4)));
typedef unsigned int uint;

#define LOG2E 1.4426950408889634f
#define NSC   (-LOG2E)               // gate pre-scale factor baked into weights

__device__ __forceinline__ uint pack2(float lo, float hi) {
    return __builtin_bit_cast(uint, __builtin_amdgcn_cvt_pkrtz(lo, hi));
}
__device__ __forceinline__ f32x4 mfma16(uint4 a, uint4 b, f32x4 c) {
    return __builtin_amdgcn_mfma_f32_16x16x32_f16(
        __builtin_bit_cast(f16x8, a), __builtin_bit_cast(f16x8, b), c, 0, 0, 0);
}
// Barrier draining ONLY LDS ops — global gathers stay outstanding.
__device__ __forceinline__ void barrier_lds() {
    asm volatile("s_waitcnt lgkmcnt(0)\n\ts_barrier" ::: "memory");
}
__device__ __forceinline__ float sigm_exact(float x) {
    return 1.0f / (1.0f + __expf(-x));
}

// LSTM cell epilogue on pre-scaled gate inputs (zs = -log2e * z).
// Exact rational form: 5 exp2 + 2 rcp (vs 10 trans in the sigmoid/tanh form).
//   A=e^-i, B=e^-f, G=e^{2g}, C=e^-o
//   c' = [c*(1+A)(G+1) + (G-1)(1+B)] / [(1+A)(G+1)(1+B)]
//   h  = (T-1)/[(1+C)(T+1)],  T=e^{2c'}
__device__ __forceinline__ float lstm_epi(float zsI, float zsF, float zsG,
                                          float zsO, float& c) {
    float A = __builtin_amdgcn_exp2f(zsI);
    float B = __builtin_amdgcn_exp2f(zsF);
    float G = __builtin_amdgcn_exp2f(-2.0f * zsG);
    float C = __builtin_amdgcn_exp2f(zsO);
    float Bp = 1.0f + B;
    float P  = (1.0f + A) * (G + 1.0f);
    float Q  = (G - 1.0f) * Bp;
    c = __builtin_fmaf(c, P, Q) * __builtin_amdgcn_rcpf(P * Bp);
    float T = __builtin_amdgcn_exp2f((2.0f * LOG2E) * c);
    return (T - 1.0f) * __builtin_amdgcn_rcpf((1.0f + C) * (T + 1.0f));
}

// ---------------- workspace layout (bytes) ----------------
#define WS_E1F_OFF 0                 // VOCAB*256 f32  = 10,240,000
#define WS_B1F_OFF 10240000          // 2048 uint4     = 32,768
#define WS_B2F_OFF 10272768          // 4096 uint4     = 65,536
#define WS_NEEDED  10338304

// ---------------- prep_e1: E1 GEMM (MFMA) + B-fragment packing ----------------
// Role A (blocks 0..NB_GEMM-1): E1f[v*256 + u*4 + g] = NSC*(b1 + emb[v] @ W1),
//   via mfma_f32_16x16x32_f16 with the NSC scale baked into the W1 fragments
//   and bias. 64 vocab rows per block (4 m-tiles of 16); each wave owns 64 raw
//   output cols. K=100 padded to 128 with zeros.
// Role B (blocks NB_GEMM..NB_GEMM+63): B1f/B2f packing, values scaled by NSC.
#define NB_GEMM 160
__global__ __launch_bounds__(256) void prep_e1(
    const float* __restrict__ emb,
    const float* __restrict__ W1, const float* __restrict__ U1,
    const float* __restrict__ b1,
    const float* __restrict__ W2, const float* __restrict__ U2,
    float* __restrict__ E1f, uint* __restrict__ B1f, uint* __restrict__ B2f) {
    if (blockIdx.x < NB_GEMM) {
        const int tid  = threadIdx.x;
        const int w    = tid >> 6;
        const int lane = tid & 63;
        const int q    = lane >> 4;
        const int li   = lane & 15;
        const int v0b  = blockIdx.x * 64;
        if (v0b >= VOCAB) return;                 // no barriers in this kernel

        // ---- pack this wave's W1 fragments (cols w*64..w*64+63), NSC-scaled ----
        uint4 bf[4][4];                           // [nf][kt]
#pragma unroll
        for (int nf = 0; nf < 4; ++nf) {
            const int col = w * 64 + nf * 16 + li;
#pragma unroll
            for (int kt = 0; kt < 4; ++kt) {
                const int k0 = kt * 32 + q * 8;
                uint dwv[4];
#pragma unroll
                for (int dw = 0; dw < 4; ++dw) {
                    const int k = k0 + 2 * dw;
                    float lo = (k     < EMB) ? NSC * W1[k * 256 + col]       : 0.0f;
                    float hi = (k + 1 < EMB) ? NSC * W1[(k + 1) * 256 + col] : 0.0f;
                    dwv[dw] = pack2(lo, hi);
                }
                bf[nf][kt].x = dwv[0]; bf[nf][kt].y = dwv[1];
                bf[nf][kt].z = dwv[2]; bf[nf][kt].w = dwv[3];
            }
        }
        float b1v[4];
#pragma unroll
        for (int nf = 0; nf < 4; ++nf) b1v[nf] = NSC * b1[w * 64 + nf * 16 + li];

#pragma unroll 1
        for (int mt = 0; mt < 4; ++mt) {
            const int v0 = v0b + mt * 16;
            if (v0 >= VOCAB) break;
            const int vr = v0 + li;               // A row this lane supplies
            const float* er = emb + (size_t)((vr < VOCAB) ? vr : (VOCAB - 1)) * EMB;

            // ---- A fragments: emb rows, f32 -> f16 (rtz) ----
            uint4 af[4];
#pragma unroll
            for (int kt = 0; kt < 3; ++kt) {
                const int k0 = kt * 32 + q * 8;   // 32B-aligned within row
                float4 lo4 = *(const float4*)(er + k0);
                float4 hi4 = *(const float4*)(er + k0 + 4);
                af[kt].x = pack2(lo4.x, lo4.y);
                af[kt].y = pack2(lo4.z, lo4.w);
                af[kt].z = pack2(hi4.x, hi4.y);
                af[kt].w = pack2(hi4.z, hi4.w);
            }
            if (q == 0) {                         // kt=3: only k=96..99 valid
                float4 t = *(const float4*)(er + 96);
                af[3].x = pack2(t.x, t.y);
                af[3].y = pack2(t.z, t.w);
                af[3].z = 0u; af[3].w = 0u;
            } else {
                af[3].x = 0u; af[3].y = 0u; af[3].z = 0u; af[3].w = 0u;
            }

            // ---- accumulate: C init = scaled bias, 16 MFMAs over K=128 ----
            f32x4 acc[4];
#pragma unroll
            for (int nf = 0; nf < 4; ++nf) {
                acc[nf][0] = b1v[nf]; acc[nf][1] = b1v[nf];
                acc[nf][2] = b1v[nf]; acc[nf][3] = b1v[nf];
            }
#pragma unroll
            for (int kt = 0; kt < 4; ++kt)
#pragma unroll
                for (int nf = 0; nf < 4; ++nf)
                    acc[nf] = mfma16(af[kt], bf[nf][kt], acc[nf]);

            // ---- store through the [v][u][g] permutation (raw col n=g*64+u) ----
            const bool full = (v0 + 16 <= VOCAB);
#pragma unroll
            for (int nf = 0; nf < 4; ++nf) {
                const int dst = (nf * 16 + li) * 4 + w;   // = (n&63)*4 + (n>>6)
#pragma unroll
                for (int reg = 0; reg < 4; ++reg) {
                    const int r = v0 + q * 4 + reg;       // C row = (lane>>4)*4+reg
                    if (full || r < VOCAB)
                        E1f[(size_t)r * 256 + dst] = acc[nf][reg];
                }
            }
        }
    } else {
        // role B: B-fragment packing (16x16x32 f16 layout: lane holds
        // B[k = kt*32 + (lane>>4)*8 + j][n = lane&15], dword dw: j=2dw lo, 2dw+1 hi)
        // Values scaled by NSC so the MFMA emits zs = -log2e * z.
        int idx = (blockIdx.x - NB_GEMM) * 256 + threadIdx.x;   // 0..16383
        if (idx < 8192) {                                     // B1f (U1, 64x256)
            int dw = idx & 3, lane = (idx >> 2) & 63, kt = (idx >> 8) & 1,
                g = (idx >> 9) & 3, w = idx >> 11;
            int k   = kt * 32 + (lane >> 4) * 8 + dw * 2;
            int col = g * 64 + w * 16 + (lane & 15);
            B1f[idx] = pack2(NSC * U1[k * 256 + col], NSC * U1[(k + 1) * 256 + col]);
        }
        if (idx < 16384) {                                    // B2f ([W2;U2], 128x256)
            int dw = idx & 3, lane = (idx >> 2) & 63, kt = (idx >> 8) & 3,
                g = (idx >> 10) & 3, w = idx >> 12;
            int k   = kt * 32 + (lane >> 4) * 8 + dw * 2;
            int col = g * 64 + w * 16 + (lane & 15);
            float lo = (k < 64) ? W2[k * 256 + col] : U2[(k - 64) * 256 + col];
            float hi = (k < 63) ? W2[(k + 1) * 256 + col] : U2[(k + 1 - 64) * 256 + col];
            B2f[idx] = pack2(NSC * lo, NSC * hi);
        }
    }
}

// ---------------- fused 2-layer LSTM + head, cross-step pipelined, full-M ----------------
__global__ __launch_bounds__(256, 1) void lstm_mfma(
    const int* __restrict__ tokens, const f32x4* __restrict__ E1f4,
    const uint4* __restrict__ B1f, const uint4* __restrict__ B2f,
    const float* __restrict__ b2, const float* __restrict__ Wd,
    const float* __restrict__ bd, float* __restrict__ out) {
    __shared__ uint4 AbufU[512];                  // 2 bufs x 256 uint4 = 8 KB
    __shared__ float red[64];
    f16* Abuf = (f16*)AbufU;

    const int tid  = threadIdx.x;
    const int w    = tid >> 6;
    const int lane = tid & 63;
    const int q    = lane >> 4;
    const int li   = lane & 15;
    const int u    = w * 16 + li;                 // this lane's unit (output col)
    const int row0 = blockIdx.x * 16;

    const uint4 z4 = {0u, 0u, 0u, 0u};
    AbufU[tid] = z4; AbufU[tid + 256] = z4;       // zero both buffers (h2(-1)=0 read)

    // persistent B fragments (96 VGPRs)
    uint4 b1f[4][2], b2f[4][4];
#pragma unroll
    for (int g = 0; g < 4; ++g) {
#pragma unroll
        for (int kt = 0; kt < 2; ++kt) b1f[g][kt] = B1f[((w * 4 + g) * 2 + kt) * 64 + lane];
#pragma unroll
        for (int kt = 0; kt < 4; ++kt) b2f[g][kt] = B2f[((w * 4 + g) * 4 + kt) * 64 + lane];
    }
    float b2v[4];
#pragma unroll
    for (int g = 0; g < 4; ++g) b2v[g] = NSC * b2[g * 64 + u];   // pre-scaled bias
    const float wdv = Wd[u];
    const float bdv = bd[0];

    // token window + depth-2 E1 prefetch (e1buf[t&1] holds step t's rows)
    // lane's rows: batch row0 + 4q + r, r = 0..3 (== C-fragment reg index)
    int4  tokc[4], tokn[4];
    f32x4 e1buf[2][4];
#pragma unroll
    for (int r = 0; r < 4; ++r) {
        tokc[r] = *(const int4*)(tokens + (size_t)(row0 + q * 4 + r) * SEQ);
        e1buf[0][r] = E1f4[(size_t)tokc[r].x * 64 + u];
        e1buf[1][r] = E1f4[(size_t)tokc[r].y * 64 + u];
    }

    float c1[4] = {0.f, 0.f, 0.f, 0.f}, c2[4] = {0.f, 0.f, 0.f, 0.f};
    float h2v[4] = {0.f, 0.f, 0.f, 0.f};
    // pipelined fragment registers: h1(t-1) and h2(t-2) (seeded 0 for t=0)
    uint4 a1f0 = z4, a1f1 = z4, a2f0 = z4, a2f1 = z4;

    __syncthreads();                              // init barrier (full drain, once)

#pragma unroll 1
    for (int t4 = 0; t4 < SEQ / 4; ++t4) {
        if (t4 < SEQ / 4 - 1) {
#pragma unroll
            for (int r = 0; r < 4; ++r)
                tokn[r] = *(const int4*)(tokens + (size_t)(row0 + q * 4 + r) * SEQ + (t4 + 1) * 4);
        }
#pragma unroll
        for (int s = 0; s < 4; ++s) {
            const int p = s & 1;                  // == t&1 (t4*4 is even)
            // ---- MFMA1(t): zs1 = e1(t) (in C) + h1(t-1) @ U1s — all registers ----
            f32x4 acc[4];
#pragma unroll
            for (int g = 0; g < 4; ++g) {
#pragma unroll
                for (int r = 0; r < 4; ++r) acc[g][r] = e1buf[p][r][g];
            }
#pragma unroll
            for (int g = 0; g < 4; ++g) acc[g] = mfma16(a1f0, b1f[g][0], acc[g]);
#pragma unroll
            for (int g = 0; g < 4; ++g) acc[g] = mfma16(a1f1, b1f[g][1], acc[g]);

            // ---- MFMA2(t-1): zs2 = b2s (in C) + [h1(t-1) | h2(t-2)] @ [W2;U2]s ----
            // (at t=0 this computes garbage that epi2 discards — frags are zero)
            f32x4 acc2[4];
#pragma unroll
            for (int g = 0; g < 4; ++g) {
                acc2[g][0] = b2v[g]; acc2[g][1] = b2v[g];
                acc2[g][2] = b2v[g]; acc2[g][3] = b2v[g];
            }
#pragma unroll
            for (int g = 0; g < 4; ++g) acc2[g] = mfma16(a1f0, b2f[g][0], acc2[g]);
#pragma unroll
            for (int g = 0; g < 4; ++g) acc2[g] = mfma16(a1f1, b2f[g][1], acc2[g]);
#pragma unroll
            for (int g = 0; g < 4; ++g) acc2[g] = mfma16(a2f0, b2f[g][2], acc2[g]);
#pragma unroll
            for (int g = 0; g < 4; ++g) acc2[g] = mfma16(a2f1, b2f[g][3], acc2[g]);

            // ---- epi1(t): h1(t) -> buf[p].h1 (tile-row m = 4q+r) ----
#pragma unroll
            for (int r = 0; r < 4; ++r) {
                float h1 = lstm_epi(acc[0][r], acc[1][r], acc[2][r], acc[3][r], c1[r]);
                Abuf[p * 2048 + ((u >> 3) * 16 + 4 * q + r) * 8 + (u & 7)] = (f16)h1;
            }

            // ---- epi2(t-1): h2(t-1) -> buf[p].h2 — SKIP at t==0 (h2(-1)=0) ----
            if (t4 | s) {
#pragma unroll
                for (int r = 0; r < 4; ++r) {
                    h2v[r] = lstm_epi(acc2[0][r], acc2[1][r], acc2[2][r], acc2[3][r], c2[r]);
                    Abuf[p * 2048 + 1024 + ((u >> 3) * 16 + 4 * q + r) * 8 + (u & 7)] = (f16)h2v[r];
                }
            }

            // gather e1 for t+2 (registers only — pre-barrier, max in-flight)
            if (t4 * 4 + s + 2 < SEQ) {
#pragma unroll
                for (int r = 0; r < 4; ++r) {
                    int tk = (s == 0) ? tokc[r].z : (s == 1) ? tokc[r].w
                           : (s == 2) ? tokn[r].x : tokn[r].y;
                    e1buf[p][r] = E1f4[(size_t)tk * 64 + u];
                }
            }

            barrier_lds();                        // end-of-step; lgkm-only

            // ds_read next epoch's frags: h1(t), h2(t-1) — consumed NEXT iteration
            a1f0 = AbufU[p * 256 + lane];
            a1f1 = AbufU[p * 256 + 64 + lane];
            a2f0 = AbufU[p * 256 + 128 + lane];
            a2f1 = AbufU[p * 256 + 192 + lane];
        }
#pragma unroll
        for (int r = 0; r < 4; ++r) tokc[r] = tokn[r];
    }

    // ---- tail: MFMA2(79) + epi2(79) (registers only, no LDS write needed) ----
    {
        f32x4 acc2[4];
#pragma unroll
        for (int g = 0; g < 4; ++g) {
            acc2[g][0] = b2v[g]; acc2[g][1] = b2v[g];
            acc2[g][2] = b2v[g]; acc2[g][3] = b2v[g];
        }
#pragma unroll
        for (int g = 0; g < 4; ++g) acc2[g] = mfma16(a1f0, b2f[g][0], acc2[g]);
#pragma unroll
        for (int g = 0; g < 4; ++g) acc2[g] = mfma16(a1f1, b2f[g][1], acc2[g]);
#pragma unroll
        for (int g = 0; g < 4; ++g) acc2[g] = mfma16(a2f0, b2f[g][2], acc2[g]);
#pragma unroll
        for (int g = 0; g < 4; ++g) acc2[g] = mfma16(a2f1, b2f[g][3], acc2[g]);
#pragma unroll
        for (int r = 0; r < 4; ++r)
            h2v[r] = lstm_epi(acc2[0][r], acc2[1][r], acc2[2][r], acc2[3][r], c2[r]);
    }

    // ---- head: out[row] = sigmoid(sum_u h2[row][u]*Wd[u] + bd) ----
#pragma unroll
    for (int r = 0; r < 4; ++r) {
        float pv = h2v[r] * wdv;
        pv += __shfl_xor(pv, 1, 64);
        pv += __shfl_xor(pv, 2, 64);
        pv += __shfl_xor(pv, 4, 64);
        pv += __shfl_xor(pv, 8, 64);
        if (li == 0) red[w * 16 + q * 4 + r] = pv;
    }
    __syncthreads();
    if (tid < 16) {
        float sum = red[tid] + red[16 + tid] + red[32 + tid] + red[48 + tid] + bdv;
        out[row0 + tid] = sigm_exact(sum);
    }
}

// ---------------- fallback (no workspace): round-1 monolithic ----------------
__device__ __forceinline__ float lane_bcast(float v, int j) {
    return __builtin_bit_cast(float, __builtin_amdgcn_readlane(__builtin_bit_cast(int, v), j));
}
__device__ __forceinline__ float sigm_f(float x)  { return 1.0f / (1.0f + __expf(-x)); }
__device__ __forceinline__ float tanh_f(float x)  { return 2.0f / (1.0f + __expf(-2.0f * x)) - 1.0f; }

__global__ __launch_bounds__(512) void lstm_fused_fallback(
    const int* __restrict__ tokens, const float* __restrict__ emb,
    const float* __restrict__ W1, const float* __restrict__ U1, const float* __restrict__ b1,
    const float* __restrict__ W2, const float* __restrict__ U2, const float* __restrict__ b2,
    const float* __restrict__ Wd, const float* __restrict__ bd, float* __restrict__ out) {
    const int lane = threadIdx.x & 63;
    const int wave = threadIdx.x >> 6;
    const int row0 = blockIdx.x * 16 + wave * 2;
    float bias1[4], bias2[4];
#pragma unroll
    for (int g = 0; g < 4; ++g) { bias1[g] = b1[g * 64 + lane]; bias2[g] = b2[g * 64 + lane]; }
    const float wd = Wd[lane]; const float bdv = bd[0];
    float h1[2] = {0.f, 0.f}, c1[2] = {0.f, 0.f}, h2[2] = {0.f, 0.f}, c2[2] = {0.f, 0.f};
#pragma unroll 1
    for (int t = 0; t < SEQ; ++t) {
        float acc[4][2];
#pragma unroll
        for (int g = 0; g < 4; ++g) { acc[g][0] = bias1[g]; acc[g][1] = bias1[g]; }
        int tokA = __builtin_amdgcn_readfirstlane(tokens[(row0 + 0) * SEQ + t]);
        int tokB = __builtin_amdgcn_readfirstlane(tokens[(row0 + 1) * SEQ + t]);
        const float4* xA = (const float4*)(emb + (size_t)tokA * EMB);
        const float4* xB = (const float4*)(emb + (size_t)tokB * EMB);
#pragma unroll 5
        for (int d4 = 0; d4 < EMB / 4; ++d4) {
            float4 a4 = xA[d4]; float4 b4 = xB[d4];
            float av[4] = {a4.x, a4.y, a4.z, a4.w}; float bv[4] = {b4.x, b4.y, b4.z, b4.w};
#pragma unroll
            for (int e = 0; e < 4; ++e) {
                const float* wrow = W1 + (d4 * 4 + e) * 256;
#pragma unroll
                for (int g = 0; g < 4; ++g) {
                    float wv = wrow[g * 64 + lane];
                    acc[g][0] += av[e] * wv; acc[g][1] += bv[e] * wv;
                }
            }
        }
#pragma unroll 4
        for (int j = 0; j < 64; ++j) {
            float ha = lane_bcast(h1[0], j), hb = lane_bcast(h1[1], j);
            const float* urow = U1 + j * 256;
#pragma unroll
            for (int g = 0; g < 4; ++g) {
                float wv = urow[g * 64 + lane];
                acc[g][0] += ha * wv; acc[g][1] += hb * wv;
            }
        }
#pragma unroll
        for (int r = 0; r < 2; ++r) {
            float ig = sigm_f(acc[0][r]), fg = sigm_f(acc[1][r]);
            float gg = tanh_f(acc[2][r]), og = sigm_f(acc[3][r]);
            c1[r] = fg * c1[r] + ig * gg; h1[r] = og * tanh_f(c1[r]);
        }
        float acc2[4][2];
#pragma unroll
        for (int g = 0; g < 4; ++g) { acc2[g][0] = bias2[g]; acc2[g][1] = bias2[g]; }
#pragma unroll 4
        for (int j = 0; j < 64; ++j) {
            float pa = lane_bcast(h1[0], j), pb = lane_bcast(h1[1], j);
            float qa = lane_bcast(h2[0], j), qb = lane_bcast(h2[1], j);
            const float* w2row = W2 + j * 256; const float* u2row = U2 + j * 256;
#pragma unroll
            for (int g = 0; g < 4; ++g) {
                float w2v = w2row[g * 64 + lane], u2v = u2row[g * 64 + lane];
                acc2[g][0] += pa * w2v + qa * u2v;
                acc2[g][1] += pb * w2v + qb * u2v;
            }
        }
#pragma unroll
        for (int r = 0; r < 2; ++r) {
            float ig = sigm_f(acc2[0][r]), fg = sigm_f(acc2[1][r]);
            float gg = tanh_f(acc2[2][r]), og = sigm_f(acc2[3][r]);
            c2[r] = fg * c2[r] + ig * gg; h2[r] = og * tanh_f(c2[r]);
        }
    }
#pragma unroll
    for (int r = 0; r < 2; ++r) {
        float p = h2[r] * wd;
#pragma unroll
        for (int off = 32; off > 0; off >>= 1) p += __shfl_down(p, off, 64);
        if (lane == 0) out[row0 + r] = sigm_f(p + bdv);
    }
}

extern "C" void kernel_launch(void* const* d_in, const int* in_sizes, int n_in,
                              void* d_out, int out_size, void* d_ws, size_t ws_size,
                              hipStream_t stream) {
    const int*   tokens = (const int*)  d_in[0];
    const float* emb    = (const float*)d_in[1];
    const float* W1     = (const float*)d_in[2];
    const float* U1     = (const float*)d_in[3];
    const float* b1     = (const float*)d_in[4];
    const float* W2     = (const float*)d_in[5];
    const float* U2     = (const float*)d_in[6];
    const float* b2     = (const float*)d_in[7];
    const float* Wd     = (const float*)d_in[8];
    const float* bd     = (const float*)d_in[9];
    float* out = (float*)d_out;

    if (ws_size < (size_t)WS_NEEDED) {
        lstm_fused_fallback<<<256, 512, 0, stream>>>(tokens, emb, W1, U1, b1, W2, U2, b2, Wd, bd, out);
        return;
    }

    char*  ws  = (char*)d_ws;
    float* E1f = (float*)(ws + WS_E1F_OFF);
    uint*  B1f = (uint*) (ws + WS_B1F_OFF);
    uint*  B2f = (uint*) (ws + WS_B2F_OFF);

    prep_e1  <<<NB_GEMM + 64, 256, 0, stream>>>(emb, W1, U1, b1, W2, U2, E1f, B1f, B2f);
    lstm_mfma<<<NGRID, 256, 0, stream>>>(tokens, (const f32x4*)E1f,
                                         (const uint4*)B1f, (const uint4*)B2f,
                                         b2, Wd, bd, out);
}

// Round 5
// 165.770 us; speedup vs baseline: 1.0021x; 1.0021x over previous
//
#include <hip/hip_runtime.h>

// LstmSequential round 16b: break the single-wave MFMA-issue block (compile
// fix: sched_group_barrier args must be literal constants -> template wrapper).
// r15 post-mortem: halving MFMA work (MfmaUtil 28.5->14.6) moved dur only
// -0.8%, while r13->r14's VALU cut passed through 1:1. Model: at 1 wave/SIMD
// the in-order wave stalls inside the 24-MFMA issue block (pipe accepts one
// 16x16x32 per ~19 cyc; wave cannot issue epilogue VALU past a stalled MFMA
// issue). This round interleaves independent VALU between MFMA quads and pins
// it with sched_group_barrier:
//   Phase A: MFMA1 quad / acc2-init movs / MFMA1 quad
//   Phase B: 4 x { MFMA2 quad(kt) ; epi1 row kt }   (epi1 independent of acc2)
//   Phase C: epi2 (true recurrence tail) ; Phase D: writes/gather/barrier.
// Also: g-gate columns pre-scaled by +2*log2e (prep + b2v) so G = exp2(zsG)
// directly — deletes 8 muls/step. Exact algebra; all else unchanged from r15
// (full-M 256x4-wave shape, rational epilogue, depth-2 E1 prefetch, MFMA prep).

#define VOCAB 10000
#define EMB   100
#define SEQ   80
#define BATCH 4096
#define NGRID 256

typedef _Float16 f16;
typedef _Float16 f16x8 __attribute__((ext_vector_type(8)));
typedef _Float16 half2_t __attribute__((ext_vector_type(2)));
typedef float    f32x4 __attribute__((ext_vector_type(4)));
typedef unsigned int uint;

#define LOG2E 1.4426950408889634f
#define NSC   (-LOG2E)               // sigmoid-gate pre-scale (i,f,o)
#define GSC   (2.0f * LOG2E)         // cell-gate pre-scale (g): G = exp2(zsG)

__device__ __forceinline__ uint pack2(float lo, float hi) {
    return __builtin_bit_cast(uint, __builtin_amdgcn_cvt_pkrtz(lo, hi));
}
__device__ __forceinline__ f32x4 mfma16(uint4 a, uint4 b, f32x4 c) {
    return __builtin_amdgcn_mfma_f32_16x16x32_f16(
        __builtin_bit_cast(f16x8, a), __builtin_bit_cast(f16x8, b), c, 0, 0, 0);
}
// Barrier draining ONLY LDS ops — global gathers stay outstanding.
__device__ __forceinline__ void barrier_lds() {
    asm volatile("s_waitcnt lgkmcnt(0)\n\ts_barrier" ::: "memory");
}
template <int MASK, int N>
__device__ __forceinline__ void sgb() {
    __builtin_amdgcn_sched_group_barrier(MASK, N, 0);
}
__device__ __forceinline__ float sigm_exact(float x) {
    return 1.0f / (1.0f + __expf(-x));
}

// LSTM cell epilogue on pre-scaled gate inputs:
//   zsI,zsF,zsO = -log2e * z   (sigmoid gates)
//   zsG         = +2*log2e * z (cell gate) -> G = exp2(zsG) = e^{2g}
// Exact rational form: 5 exp2 + 2 rcp.
//   A=e^-i, B=e^-f, C=e^-o
//   c' = [c*(1+A)(G+1) + (G-1)(1+B)] / [(1+A)(G+1)(1+B)]
//   h  = (T-1)/[(1+C)(T+1)],  T=e^{2c'}
__device__ __forceinline__ float lstm_epi(float zsI, float zsF, float zsG,
                                          float zsO, float& c) {
    float A = __builtin_amdgcn_exp2f(zsI);
    float B = __builtin_amdgcn_exp2f(zsF);
    float G = __builtin_amdgcn_exp2f(zsG);
    float C = __builtin_amdgcn_exp2f(zsO);
    float Bp = 1.0f + B;
    float P  = (1.0f + A) * (G + 1.0f);
    float Q  = (G - 1.0f) * Bp;
    c = __builtin_fmaf(c, P, Q) * __builtin_amdgcn_rcpf(P * Bp);
    float T = __builtin_amdgcn_exp2f((2.0f * LOG2E) * c);
    return (T - 1.0f) * __builtin_amdgcn_rcpf((1.0f + C) * (T + 1.0f));
}

// ---------------- workspace layout (bytes) ----------------
#define WS_E1F_OFF 0                 // VOCAB*256 f32  = 10,240,000
#define WS_B1F_OFF 10240000          // 2048 uint4     = 32,768
#define WS_B2F_OFF 10272768          // 4096 uint4     = 65,536
#define WS_NEEDED  10338304

// ---------------- prep_e1: E1 GEMM (MFMA) + B-fragment packing ----------------
// Role A (blocks 0..NB_GEMM-1): E1f[v*256 + u*4 + g] = sc_g*(b1 + emb[v] @ W1),
//   sc_g = NSC for gates i,f,o and GSC for gate g. In role A each wave owns one
//   gate's 64 raw cols (col = w*64 + nf*16 + li -> gate = w). K padded 100->128.
// Role B (blocks NB_GEMM..NB_GEMM+63): B1f/B2f packing, same per-gate scales.
#define NB_GEMM 160
__global__ __launch_bounds__(256) void prep_e1(
    const float* __restrict__ emb,
    const float* __restrict__ W1, const float* __restrict__ U1,
    const float* __restrict__ b1,
    const float* __restrict__ W2, const float* __restrict__ U2,
    float* __restrict__ E1f, uint* __restrict__ B1f, uint* __restrict__ B2f) {
    if (blockIdx.x < NB_GEMM) {
        const int tid  = threadIdx.x;
        const int w    = tid >> 6;
        const int lane = tid & 63;
        const int q    = lane >> 4;
        const int li   = lane & 15;
        const int v0b  = blockIdx.x * 64;
        if (v0b >= VOCAB) return;                 // no barriers in this kernel

        const float sc = (w == 2) ? GSC : NSC;    // per-gate scale (gate = w)

        // ---- pack this wave's W1 fragments (cols w*64..w*64+63), scaled ----
        uint4 bf[4][4];                           // [nf][kt]
#pragma unroll
        for (int nf = 0; nf < 4; ++nf) {
            const int col = w * 64 + nf * 16 + li;
#pragma unroll
            for (int kt = 0; kt < 4; ++kt) {
                const int k0 = kt * 32 + q * 8;
                uint dwv[4];
#pragma unroll
                for (int dw = 0; dw < 4; ++dw) {
                    const int k = k0 + 2 * dw;
                    float lo = (k     < EMB) ? sc * W1[k * 256 + col]       : 0.0f;
                    float hi = (k + 1 < EMB) ? sc * W1[(k + 1) * 256 + col] : 0.0f;
                    dwv[dw] = pack2(lo, hi);
                }
                bf[nf][kt].x = dwv[0]; bf[nf][kt].y = dwv[1];
                bf[nf][kt].z = dwv[2]; bf[nf][kt].w = dwv[3];
            }
        }
        float b1v[4];
#pragma unroll
        for (int nf = 0; nf < 4; ++nf) b1v[nf] = sc * b1[w * 64 + nf * 16 + li];

#pragma unroll 1
        for (int mt = 0; mt < 4; ++mt) {
            const int v0 = v0b + mt * 16;
            if (v0 >= VOCAB) break;
            const int vr = v0 + li;               // A row this lane supplies
            const float* er = emb + (size_t)((vr < VOCAB) ? vr : (VOCAB - 1)) * EMB;

            // ---- A fragments: emb rows, f32 -> f16 (rtz) ----
            uint4 af[4];
#pragma unroll
            for (int kt = 0; kt < 3; ++kt) {
                const int k0 = kt * 32 + q * 8;   // 32B-aligned within row
                float4 lo4 = *(const float4*)(er + k0);
                float4 hi4 = *(const float4*)(er + k0 + 4);
                af[kt].x = pack2(lo4.x, lo4.y);
                af[kt].y = pack2(lo4.z, lo4.w);
                af[kt].z = pack2(hi4.x, hi4.y);
                af[kt].w = pack2(hi4.z, hi4.w);
            }
            if (q == 0) {                         // kt=3: only k=96..99 valid
                float4 t = *(const float4*)(er + 96);
                af[3].x = pack2(t.x, t.y);
                af[3].y = pack2(t.z, t.w);
                af[3].z = 0u; af[3].w = 0u;
            } else {
                af[3].x = 0u; af[3].y = 0u; af[3].z = 0u; af[3].w = 0u;
            }

            // ---- accumulate: C init = scaled bias, 16 MFMAs over K=128 ----
            f32x4 acc[4];
#pragma unroll
            for (int nf = 0; nf < 4; ++nf) {
                acc[nf][0] = b1v[nf]; acc[nf][1] = b1v[nf];
                acc[nf][2] = b1v[nf]; acc[nf][3] = b1v[nf];
            }
#pragma unroll
            for (int kt = 0; kt < 4; ++kt)
#pragma unroll
                for (int nf = 0; nf < 4; ++nf)
                    acc[nf] = mfma16(af[kt], bf[nf][kt], acc[nf]);

            // ---- store through the [v][u][g] permutation (raw col n=g*64+u) ----
            const bool full = (v0 + 16 <= VOCAB);
#pragma unroll
            for (int nf = 0; nf < 4; ++nf) {
                const int dst = (nf * 16 + li) * 4 + w;   // = (n&63)*4 + (n>>6)
#pragma unroll
                for (int reg = 0; reg < 4; ++reg) {
                    const int r = v0 + q * 4 + reg;       // C row = (lane>>4)*4+reg
                    if (full || r < VOCAB)
                        E1f[(size_t)r * 256 + dst] = acc[nf][reg];
                }
            }
        }
    } else {
        // role B: B-fragment packing (16x16x32 f16 layout: lane holds
        // B[k = kt*32 + (lane>>4)*8 + j][n = lane&15], dword dw: j=2dw lo, 2dw+1 hi)
        // Values scaled per-gate: NSC (i,f,o) / GSC (g).
        int idx = (blockIdx.x - NB_GEMM) * 256 + threadIdx.x;   // 0..16383
        if (idx < 8192) {                                     // B1f (U1, 64x256)
            int dw = idx & 3, lane = (idx >> 2) & 63, kt = (idx >> 8) & 1,
                g = (idx >> 9) & 3, w = idx >> 11;
            int k   = kt * 32 + (lane >> 4) * 8 + dw * 2;
            int col = g * 64 + w * 16 + (lane & 15);
            float sc = (g == 2) ? GSC : NSC;
            B1f[idx] = pack2(sc * U1[k * 256 + col], sc * U1[(k + 1) * 256 + col]);
        }
        if (idx < 16384) {                                    // B2f ([W2;U2], 128x256)
            int dw = idx & 3, lane = (idx >> 2) & 63, kt = (idx >> 8) & 3,
                g = (idx >> 10) & 3, w = idx >> 12;
            int k   = kt * 32 + (lane >> 4) * 8 + dw * 2;
            int col = g * 64 + w * 16 + (lane & 15);
            float sc = (g == 2) ? GSC : NSC;
            float lo = (k < 64) ? W2[k * 256 + col] : U2[(k - 64) * 256 + col];
            float hi = (k < 63) ? W2[(k + 1) * 256 + col] : U2[(k + 1 - 64) * 256 + col];
            B2f[idx] = pack2(sc * lo, sc * hi);
        }
    }
}

// ---------------- fused 2-layer LSTM + head, cross-step pipelined, full-M ----------------
// A-buffer (2 bufs, p=t&1): fp16 A-matrix [16 m x 128 k] in fragment layout,
//   f16 index of (m,k) = ((k>>3)*16 + m)*8 + (k&7); lane's kt-frag = uint4
//   [kt*64+lane]. k 0..63 = h1, k 64..127 = h2. Tile-row m = 4q+r <-> batch row
//   row0 + 4q + r.
__global__ __launch_bounds__(256, 1) void lstm_mfma(
    const int* __restrict__ tokens, const f32x4* __restrict__ E1f4,
    const uint4* __restrict__ B1f, const uint4* __restrict__ B2f,
    const float* __restrict__ b2, const float* __restrict__ Wd,
    const float* __restrict__ bd, float* __restrict__ out) {
    __shared__ uint4 AbufU[512];                  // 2 bufs x 256 uint4 = 8 KB
    __shared__ float red[64];
    f16* Abuf = (f16*)AbufU;

    const int tid  = threadIdx.x;
    const int w    = tid >> 6;
    const int lane = tid & 63;
    const int q    = lane >> 4;
    const int li   = lane & 15;
    const int u    = w * 16 + li;                 // this lane's unit (output col)
    const int row0 = blockIdx.x * 16;

    const uint4 z4 = {0u, 0u, 0u, 0u};
    AbufU[tid] = z4; AbufU[tid + 256] = z4;       // zero both buffers (h2(-1)=0 read)

    // persistent B fragments (96 VGPRs)
    uint4 b1f[4][2], b2f[4][4];
#pragma unroll
    for (int g = 0; g < 4; ++g) {
#pragma unroll
        for (int kt = 0; kt < 2; ++kt) b1f[g][kt] = B1f[((w * 4 + g) * 2 + kt) * 64 + lane];
#pragma unroll
        for (int kt = 0; kt < 4; ++kt) b2f[g][kt] = B2f[((w * 4 + g) * 4 + kt) * 64 + lane];
    }
    float b2v[4];
#pragma unroll
    for (int g = 0; g < 4; ++g)
        b2v[g] = ((g == 2) ? GSC : NSC) * b2[g * 64 + u];   // pre-scaled bias
    const float wdv = Wd[u];
    const float bdv = bd[0];

    // token window + depth-2 E1 prefetch (e1buf[t&1] holds step t's rows)
    // lane's rows: batch row0 + 4q + r, r = 0..3 (== C-fragment reg index)
    int4  tokc[4], tokn[4];
    f32x4 e1buf[2][4];
#pragma unroll
    for (int r = 0; r < 4; ++r) {
        tokc[r] = *(const int4*)(tokens + (size_t)(row0 + q * 4 + r) * SEQ);
        e1buf[0][r] = E1f4[(size_t)tokc[r].x * 64 + u];
        e1buf[1][r] = E1f4[(size_t)tokc[r].y * 64 + u];
    }

    float c1[4] = {0.f, 0.f, 0.f, 0.f}, c2[4] = {0.f, 0.f, 0.f, 0.f};
    float h2v[4] = {0.f, 0.f, 0.f, 0.f};
    // pipelined fragment registers: h1(t-1) and h2(t-2) (seeded 0 for t=0)
    uint4 a1f0 = z4, a1f1 = z4, a2f0 = z4, a2f1 = z4;

    __syncthreads();                              // init barrier (full drain, once)

#pragma unroll 1
    for (int t4 = 0; t4 < SEQ / 4; ++t4) {
        if (t4 < SEQ / 4 - 1) {
#pragma unroll
            for (int r = 0; r < 4; ++r)
                tokn[r] = *(const int4*)(tokens + (size_t)(row0 + q * 4 + r) * SEQ + (t4 + 1) * 4);
        }
#pragma unroll
        for (int s = 0; s < 4; ++s) {
            const int p = s & 1;                  // == t&1 (t4*4 is even)

            // ---- Phase A: MFMA1(t) with acc2-init movs between quads ----
            f32x4 acc[4], acc2[4];
#pragma unroll
            for (int g = 0; g < 4; ++g) {
#pragma unroll
                for (int r = 0; r < 4; ++r) acc[g][r] = e1buf[p][r][g];
            }
#pragma unroll
            for (int g = 0; g < 4; ++g) acc[g] = mfma16(a1f0, b1f[g][0], acc[g]);
#pragma unroll
            for (int g = 0; g < 4; ++g) {
                acc2[g][0] = b2v[g]; acc2[g][1] = b2v[g];
                acc2[g][2] = b2v[g]; acc2[g][3] = b2v[g];
            }
#pragma unroll
            for (int g = 0; g < 4; ++g) acc[g] = mfma16(a1f1, b1f[g][1], acc[g]);

            // ---- Phase B: 4 x { MFMA2 quad(kt) ; epi1 row kt } ----
            // epi1 row kt is independent of acc2 — fills the MFMA2 pipe time.
#pragma unroll
            for (int kt = 0; kt < 4; ++kt) {
                const uint4 af = (kt == 0) ? a1f0 : (kt == 1) ? a1f1
                               : (kt == 2) ? a2f0 : a2f1;
#pragma unroll
                for (int g = 0; g < 4; ++g) acc2[g] = mfma16(af, b2f[g][kt], acc2[g]);
                float h1 = lstm_epi(acc[0][kt], acc[1][kt], acc[2][kt], acc[3][kt], c1[kt]);
                Abuf[p * 2048 + ((u >> 3) * 16 + 4 * q + kt) * 8 + (u & 7)] = (f16)h1;
            }

            // ---- Phase C: epi2(t-1) — SKIP at t==0 (h2(-1)=0) ----
            if (t4 | s) {
#pragma unroll
                for (int r = 0; r < 4; ++r) {
                    h2v[r] = lstm_epi(acc2[0][r], acc2[1][r], acc2[2][r], acc2[3][r], c2[r]);
                    Abuf[p * 2048 + 1024 + ((u >> 3) * 16 + 4 * q + r) * 8 + (u & 7)] = (f16)h2v[r];
                }
            }

            // ---- Phase D: gather e1 for t+2 (pre-barrier, max in-flight) ----
            if (t4 * 4 + s + 2 < SEQ) {
#pragma unroll
                for (int r = 0; r < 4; ++r) {
                    int tk = (s == 0) ? tokc[r].z : (s == 1) ? tokc[r].w
                           : (s == 2) ? tokn[r].x : tokn[r].y;
                    e1buf[p][r] = E1f4[(size_t)tk * 64 + u];
                }
            }

            // ---- scheduling template: pin MFMA/VALU interleave for A+B ----
            sgb<0x2, 16>(); sgb<0x8, 4>();        // acc-init movs | MFMA1 kt0
            sgb<0x2, 16>(); sgb<0x8, 4>();        // acc2-init movs | MFMA1 kt1
            sgb<0x8, 4>(); sgb<0x2, 40>();        // MFMA2 quad kt0 | epi1 row 0
            sgb<0x8, 4>(); sgb<0x2, 40>();        // MFMA2 quad kt1 | epi1 row 1
            sgb<0x8, 4>(); sgb<0x2, 40>();        // MFMA2 quad kt2 | epi1 row 2
            sgb<0x8, 4>(); sgb<0x2, 40>();        // MFMA2 quad kt3 | epi1 row 3
            // remainder (epi2, writes, gather) left to the scheduler

            barrier_lds();                        // end-of-step; lgkm-only

            // ds_read next epoch's frags: h1(t), h2(t-1) — consumed NEXT iteration
            a1f0 = AbufU[p * 256 + lane];
            a1f1 = AbufU[p * 256 + 64 + lane];
            a2f0 = AbufU[p * 256 + 128 + lane];
            a2f1 = AbufU[p * 256 + 192 + lane];
        }
#pragma unroll
        for (int r = 0; r < 4; ++r) tokc[r] = tokn[r];
    }

    // ---- tail: MFMA2(79) + epi2(79) (registers only, no LDS write needed) ----
    {
        f32x4 acc2[4];
#pragma unroll
        for (int g = 0; g < 4; ++g) {
            acc2[g][0] = b2v[g]; acc2[g][1] = b2v[g];
            acc2[g][2] = b2v[g]; acc2[g][3] = b2v[g];
        }
#pragma unroll
        for (int g = 0; g < 4; ++g) acc2[g] = mfma16(a1f0, b2f[g][0], acc2[g]);
#pragma unroll
        for (int g = 0; g < 4; ++g) acc2[g] = mfma16(a1f1, b2f[g][1], acc2[g]);
#pragma unroll
        for (int g = 0; g < 4; ++g) acc2[g] = mfma16(a2f0, b2f[g][2], acc2[g]);
#pragma unroll
        for (int g = 0; g < 4; ++g) acc2[g] = mfma16(a2f1, b2f[g][3], acc2[g]);
#pragma unroll
        for (int r = 0; r < 4; ++r)
            h2v[r] = lstm_epi(acc2[0][r], acc2[1][r], acc2[2][r], acc2[3][r], c2[r]);
    }

    // ---- head: out[row] = sigmoid(sum_u h2[row][u]*Wd[u] + bd) ----
#pragma unroll
    for (int r = 0; r < 4; ++r) {
        float pv = h2v[r] * wdv;
        pv += __shfl_xor(pv, 1, 64);
        pv += __shfl_xor(pv, 2, 64);
        pv += __shfl_xor(pv, 4, 64);
        pv += __shfl_xor(pv, 8, 64);
        if (li == 0) red[w * 16 + q * 4 + r] = pv;
    }
    __syncthreads();
    if (tid < 16) {
        float sum = red[tid] + red[16 + tid] + red[32 + tid] + red[48 + tid] + bdv;
        out[row0 + tid] = sigm_exact(sum);
    }
}

// ---------------- fallback (no workspace): round-1 monolithic ----------------
__device__ __forceinline__ float lane_bcast(float v, int j) {
    return __builtin_bit_cast(float, __builtin_amdgcn_readlane(__builtin_bit_cast(int, v), j));
}
__device__ __forceinline__ float sigm_f(float x)  { return 1.0f / (1.0f + __expf(-x)); }
__device__ __forceinline__ float tanh_f(float x)  { return 2.0f / (1.0f + __expf(-2.0f * x)) - 1.0f; }

__global__ __launch_bounds__(512) void lstm_fused_fallback(
    const int* __restrict__ tokens, const float* __restrict__ emb,
    const float* __restrict__ W1, const float* __restrict__ U1, const float* __restrict__ b1,
    const float* __restrict__ W2, const float* __restrict__ U2, const float* __restrict__ b2,
    const float* __restrict__ Wd, const float* __restrict__ bd, float* __restrict__ out) {
    const int lane = threadIdx.x & 63;
    const int wave = threadIdx.x >> 6;
    const int row0 = blockIdx.x * 16 + wave * 2;
    float bias1[4], bias2[4];
#pragma unroll
    for (int g = 0; g < 4; ++g) { bias1[g] = b1[g * 64 + lane]; bias2[g] = b2[g * 64 + lane]; }
    const float wd = Wd[lane]; const float bdv = bd[0];
    float h1[2] = {0.f, 0.f}, c1[2] = {0.f, 0.f}, h2[2] = {0.f, 0.f}, c2[2] = {0.f, 0.f};
#pragma unroll 1
    for (int t = 0; t < SEQ; ++t) {
        float acc[4][2];
#pragma unroll
        for (int g = 0; g < 4; ++g) { acc[g][0] = bias1[g]; acc[g][1] = bias1[g]; }
        int tokA = __builtin_amdgcn_readfirstlane(tokens[(row0 + 0) * SEQ + t]);
        int tokB = __builtin_amdgcn_readfirstlane(tokens[(row0 + 1) * SEQ + t]);
        const float4* xA = (const float4*)(emb + (size_t)tokA * EMB);
        const float4* xB = (const float4*)(emb + (size_t)tokB * EMB);
#pragma unroll 5
        for (int d4 = 0; d4 < EMB / 4; ++d4) {
            float4 a4 = xA[d4]; float4 b4 = xB[d4];
            float av[4] = {a4.x, a4.y, a4.z, a4.w}; float bv[4] = {b4.x, b4.y, b4.z, b4.w};
#pragma unroll
            for (int e = 0; e < 4; ++e) {
                const float* wrow = W1 + (d4 * 4 + e) * 256;
#pragma unroll
                for (int g = 0; g < 4; ++g) {
                    float wv = wrow[g * 64 + lane];
                    acc[g][0] += av[e] * wv; acc[g][1] += bv[e] * wv;
                }
            }
        }
#pragma unroll 4
        for (int j = 0; j < 64; ++j) {
            float ha = lane_bcast(h1[0], j), hb = lane_bcast(h1[1], j);
            const float* urow = U1 + j * 256;
#pragma unroll
            for (int g = 0; g < 4; ++g) {
                float wv = urow[g * 64 + lane];
                acc[g][0] += ha * wv; acc[g][1] += hb * wv;
            }
        }
#pragma unroll
        for (int r = 0; r < 2; ++r) {
            float ig = sigm_f(acc[0][r]), fg = sigm_f(acc[1][r]);
            float gg = tanh_f(acc[2][r]), og = sigm_f(acc[3][r]);
            c1[r] = fg * c1[r] + ig * gg; h1[r] = og * tanh_f(c1[r]);
        }
        float acc2[4][2];
#pragma unroll
        for (int g = 0; g < 4; ++g) { acc2[g][0] = bias2[g]; acc2[g][1] = bias2[g]; }
#pragma unroll 4
        for (int j = 0; j < 64; ++j) {
            float pa = lane_bcast(h1[0], j), pb = lane_bcast(h1[1], j);
            float qa = lane_bcast(h2[0], j), qb = lane_bcast(h2[1], j);
            const float* w2row = W2 + j * 256; const float* u2row = U2 + j * 256;
#pragma unroll
            for (int g = 0; g < 4; ++g) {
                float w2v = w2row[g * 64 + lane], u2v = u2row[g * 64 + lane];
                acc2[g][0] += pa * w2v + qa * u2v;
                acc2[g][1] += pb * w2v + qb * u2v;
            }
        }
#pragma unroll
        for (int r = 0; r < 2; ++r) {
            float ig = sigm_f(acc2[0][r]), fg = sigm_f(acc2[1][r]);
            float gg = tanh_f(acc2[2][r]), og = sigm_f(acc2[3][r]);
            c2[r] = fg * c2[r] + ig * gg; h2[r] = og * tanh_f(c2[r]);
        }
    }
#pragma unroll
    for (int r = 0; r < 2; ++r) {
        float p = h2[r] * wd;
#pragma unroll
        for (int off = 32; off > 0; off >>= 1) p += __shfl_down(p, off, 64);
        if (lane == 0) out[row0 + r] = sigm_f(p + bdv);
    }
}

extern "C" void kernel_launch(void* const* d_in, const int* in_sizes, int n_in,
                              void* d_out, int out_size, void* d_ws, size_t ws_size,
                              hipStream_t stream) {
    const int*   tokens = (const int*)  d_in[0];
    const float* emb    = (const float*)d_in[1];
    const float* W1     = (const float*)d_in[2];
    const float* U1     = (const float*)d_in[3];
    const float* b1     = (const float*)d_in[4];
    const float* W2     = (const float*)d_in[5];
    const float* U2     = (const float*)d_in[6];
    const float* b2     = (const float*)d_in[7];
    const float* Wd     = (const float*)d_in[8];
    const float* bd     = (const float*)d_in[9];
    float* out = (float*)d_out;

    if (ws_size < (size_t)WS_NEEDED) {
        lstm_fused_fallback<<<256, 512, 0, stream>>>(tokens, emb, W1, U1, b1, W2, U2, b2, Wd, bd, out);
        return;
    }

    char*  ws  = (char*)d_ws;
    float* E1f = (float*)(ws + WS_E1F_OFF);
    uint*  B1f = (uint*) (ws + WS_B1F_OFF);
    uint*  B2f = (uint*) (ws + WS_B2F_OFF);

    prep_e1  <<<NB_GEMM + 64, 256, 0, stream>>>(emb, W1, U1, b1, W2, U2, E1f, B1f, B2f);
    lstm_mfma<<<NGRID, 256, 0, stream>>>(tokens, (const f32x4*)E1f,
                                         (const uint4*)B1f, (const uint4*)B2f,
                                         b2, Wd, bd, out);
}

// Round 6
// 148.621 us; speedup vs baseline: 1.1178x; 1.1154x over previous
//
#include <hip/hip_runtime.h>

// LstmSequential round 17: heterogeneous wave specialization.
// Measured ledger: VALU cuts pass 1:1 (r14); halving MFMA does nothing (r15);
// SGB issue-pinning slightly hurts (r16). So the step is latency-bound
// (~1300 cyc/step exposed) and symmetric waves are PHASE-LOCKED: same barrier,
// same code -> correlated stalls that TLP can't hide.
// This round: 512-thread blocks, 8 waves. Waves 0-3 (L1): MFMA1(t)+epi1(t)
// +E1 gather. Waves 4-7 (L2): MFMA2(t-1)+epi2(t-1)+head. Each SIMD hosts one
// L1 + one L2 wave with DIFFERENT stall profiles -> stalls decorrelate.
// Dataflow/LDS/barrier identical to r15 (one lgkm-only barrier per step;
// a1f=h1(t-1) feeds both MFMA1(t) and MFMA2(t-1)). Per-wave VGPR drops
// (each group holds only its own B-fragments). SGB pinning removed.
// Epilogue: rational form, 5 exp2 + 2 rcp, per-gate pre-scales NSC/GSC baked
// into weights (prep). Fallback: round-1 monolithic kernel.

#define VOCAB 10000
#define EMB   100
#define SEQ   80
#define BATCH 4096
#define NGRID 256

typedef _Float16 f16;
typedef _Float16 f16x8 __attribute__((ext_vector_type(8)));
typedef _Float16 half2_t __attribute__((ext_vector_type(2)));
typedef float    f32x4 __attribute__((ext_vector_type(4)));
typedef unsigned int uint;

#define LOG2E 1.4426950408889634f
#define NSC   (-LOG2E)               // sigmoid-gate pre-scale (i,f,o)
#define GSC   (2.0f * LOG2E)         // cell-gate pre-scale (g): G = exp2(zsG)

__device__ __forceinline__ uint pack2(float lo, float hi) {
    return __builtin_bit_cast(uint, __builtin_amdgcn_cvt_pkrtz(lo, hi));
}
__device__ __forceinline__ f32x4 mfma16(uint4 a, uint4 b, f32x4 c) {
    return __builtin_amdgcn_mfma_f32_16x16x32_f16(
        __builtin_bit_cast(f16x8, a), __builtin_bit_cast(f16x8, b), c, 0, 0, 0);
}
// Barrier draining ONLY LDS ops — global gathers stay outstanding.
__device__ __forceinline__ void barrier_lds() {
    asm volatile("s_waitcnt lgkmcnt(0)\n\ts_barrier" ::: "memory");
}
__device__ __forceinline__ float sigm_exact(float x) {
    return 1.0f / (1.0f + __expf(-x));
}

// LSTM cell epilogue on pre-scaled gate inputs:
//   zsI,zsF,zsO = -log2e * z   (sigmoid gates)
//   zsG         = +2*log2e * z (cell gate) -> G = exp2(zsG) = e^{2g}
// Exact rational form: 5 exp2 + 2 rcp.
//   A=e^-i, B=e^-f, C=e^-o
//   c' = [c*(1+A)(G+1) + (G-1)(1+B)] / [(1+A)(G+1)(1+B)]
//   h  = (T-1)/[(1+C)(T+1)],  T=e^{2c'}
__device__ __forceinline__ float lstm_epi(float zsI, float zsF, float zsG,
                                          float zsO, float& c) {
    float A = __builtin_amdgcn_exp2f(zsI);
    float B = __builtin_amdgcn_exp2f(zsF);
    float G = __builtin_amdgcn_exp2f(zsG);
    float C = __builtin_amdgcn_exp2f(zsO);
    float Bp = 1.0f + B;
    float P  = (1.0f + A) * (G + 1.0f);
    float Q  = (G - 1.0f) * Bp;
    c = __builtin_fmaf(c, P, Q) * __builtin_amdgcn_rcpf(P * Bp);
    float T = __builtin_amdgcn_exp2f((2.0f * LOG2E) * c);
    return (T - 1.0f) * __builtin_amdgcn_rcpf((1.0f + C) * (T + 1.0f));
}

// ---------------- workspace layout (bytes) ----------------
#define WS_E1F_OFF 0                 // VOCAB*256 f32  = 10,240,000
#define WS_B1F_OFF 10240000          // 2048 uint4     = 32,768
#define WS_B2F_OFF 10272768          // 4096 uint4     = 65,536
#define WS_NEEDED  10338304

// ---------------- prep_e1: E1 GEMM (MFMA) + B-fragment packing ----------------
// Role A (blocks 0..NB_GEMM-1): E1f[v*256 + u*4 + g] = sc_g*(b1 + emb[v] @ W1),
//   sc_g = NSC for gates i,f,o and GSC for gate g. In role A each wave owns one
//   gate's 64 raw cols (col = w*64 + nf*16 + li -> gate = w). K padded 100->128.
// Role B (blocks NB_GEMM..NB_GEMM+63): B1f/B2f packing, same per-gate scales.
#define NB_GEMM 160
__global__ __launch_bounds__(256) void prep_e1(
    const float* __restrict__ emb,
    const float* __restrict__ W1, const float* __restrict__ U1,
    const float* __restrict__ b1,
    const float* __restrict__ W2, const float* __restrict__ U2,
    float* __restrict__ E1f, uint* __restrict__ B1f, uint* __restrict__ B2f) {
    if (blockIdx.x < NB_GEMM) {
        const int tid  = threadIdx.x;
        const int w    = tid >> 6;
        const int lane = tid & 63;
        const int q    = lane >> 4;
        const int li   = lane & 15;
        const int v0b  = blockIdx.x * 64;
        if (v0b >= VOCAB) return;                 // no barriers in this kernel

        const float sc = (w == 2) ? GSC : NSC;    // per-gate scale (gate = w)

        // ---- pack this wave's W1 fragments (cols w*64..w*64+63), scaled ----
        uint4 bf[4][4];                           // [nf][kt]
#pragma unroll
        for (int nf = 0; nf < 4; ++nf) {
            const int col = w * 64 + nf * 16 + li;
#pragma unroll
            for (int kt = 0; kt < 4; ++kt) {
                const int k0 = kt * 32 + q * 8;
                uint dwv[4];
#pragma unroll
                for (int dw = 0; dw < 4; ++dw) {
                    const int k = k0 + 2 * dw;
                    float lo = (k     < EMB) ? sc * W1[k * 256 + col]       : 0.0f;
                    float hi = (k + 1 < EMB) ? sc * W1[(k + 1) * 256 + col] : 0.0f;
                    dwv[dw] = pack2(lo, hi);
                }
                bf[nf][kt].x = dwv[0]; bf[nf][kt].y = dwv[1];
                bf[nf][kt].z = dwv[2]; bf[nf][kt].w = dwv[3];
            }
        }
        float b1v[4];
#pragma unroll
        for (int nf = 0; nf < 4; ++nf) b1v[nf] = sc * b1[w * 64 + nf * 16 + li];

#pragma unroll 1
        for (int mt = 0; mt < 4; ++mt) {
            const int v0 = v0b + mt * 16;
            if (v0 >= VOCAB) break;
            const int vr = v0 + li;               // A row this lane supplies
            const float* er = emb + (size_t)((vr < VOCAB) ? vr : (VOCAB - 1)) * EMB;

            // ---- A fragments: emb rows, f32 -> f16 (rtz) ----
            uint4 af[4];
#pragma unroll
            for (int kt = 0; kt < 3; ++kt) {
                const int k0 = kt * 32 + q * 8;   // 32B-aligned within row
                float4 lo4 = *(const float4*)(er + k0);
                float4 hi4 = *(const float4*)(er + k0 + 4);
                af[kt].x = pack2(lo4.x, lo4.y);
                af[kt].y = pack2(lo4.z, lo4.w);
                af[kt].z = pack2(hi4.x, hi4.y);
                af[kt].w = pack2(hi4.z, hi4.w);
            }
            if (q == 0) {                         // kt=3: only k=96..99 valid
                float4 t = *(const float4*)(er + 96);
                af[3].x = pack2(t.x, t.y);
                af[3].y = pack2(t.z, t.w);
                af[3].z = 0u; af[3].w = 0u;
            } else {
                af[3].x = 0u; af[3].y = 0u; af[3].z = 0u; af[3].w = 0u;
            }

            // ---- accumulate: C init = scaled bias, 16 MFMAs over K=128 ----
            f32x4 acc[4];
#pragma unroll
            for (int nf = 0; nf < 4; ++nf) {
                acc[nf][0] = b1v[nf]; acc[nf][1] = b1v[nf];
                acc[nf][2] = b1v[nf]; acc[nf][3] = b1v[nf];
            }
#pragma unroll
            for (int kt = 0; kt < 4; ++kt)
#pragma unroll
                for (int nf = 0; nf < 4; ++nf)
                    acc[nf] = mfma16(af[kt], bf[nf][kt], acc[nf]);

            // ---- store through the [v][u][g] permutation (raw col n=g*64+u) ----
            const bool full = (v0 + 16 <= VOCAB);
#pragma unroll
            for (int nf = 0; nf < 4; ++nf) {
                const int dst = (nf * 16 + li) * 4 + w;   // = (n&63)*4 + (n>>6)
#pragma unroll
                for (int reg = 0; reg < 4; ++reg) {
                    const int r = v0 + q * 4 + reg;       // C row = (lane>>4)*4+reg
                    if (full || r < VOCAB)
                        E1f[(size_t)r * 256 + dst] = acc[nf][reg];
                }
            }
        }
    } else {
        // role B: B-fragment packing (16x16x32 f16 layout: lane holds
        // B[k = kt*32 + (lane>>4)*8 + j][n = lane&15], dword dw: j=2dw lo, 2dw+1 hi)
        // Values scaled per-gate: NSC (i,f,o) / GSC (g).
        int idx = (blockIdx.x - NB_GEMM) * 256 + threadIdx.x;   // 0..16383
        if (idx < 8192) {                                     // B1f (U1, 64x256)
            int dw = idx & 3, lane = (idx >> 2) & 63, kt = (idx >> 8) & 1,
                g = (idx >> 9) & 3, w = idx >> 11;
            int k   = kt * 32 + (lane >> 4) * 8 + dw * 2;
            int col = g * 64 + w * 16 + (lane & 15);
            float sc = (g == 2) ? GSC : NSC;
            B1f[idx] = pack2(sc * U1[k * 256 + col], sc * U1[(k + 1) * 256 + col]);
        }
        if (idx < 16384) {                                    // B2f ([W2;U2], 128x256)
            int dw = idx & 3, lane = (idx >> 2) & 63, kt = (idx >> 8) & 3,
                g = (idx >> 10) & 3, w = idx >> 12;
            int k   = kt * 32 + (lane >> 4) * 8 + dw * 2;
            int col = g * 64 + w * 16 + (lane & 15);
            float sc = (g == 2) ? GSC : NSC;
            float lo = (k < 64) ? W2[k * 256 + col] : U2[(k - 64) * 256 + col];
            float hi = (k < 63) ? W2[(k + 1) * 256 + col] : U2[(k + 1 - 64) * 256 + col];
            B2f[idx] = pack2(sc * lo, sc * hi);
        }
    }
}

// ---------------- fused 2-layer LSTM + head: specialized wave groups ----------------
// 512 threads = 8 waves. Waves 0-3 (L1): MFMA1(t)+epi1(t)+E1 gather for unit
// block wl=w. Waves 4-7 (L2): MFMA2(t-1)+epi2(t-1)+head for unit block wl=w-4.
// A-buffer (2 bufs, p=t&1): fp16 A-matrix [16 m x 128 k] in fragment layout,
//   f16 index of (m,k) = ((k>>3)*16 + m)*8 + (k&7); lane's kt-frag = uint4
//   [kt*64+lane]. k 0..63 = h1, k 64..127 = h2. Tile-row m = 4q+r <-> batch
//   row row0 + 4q + r. Same dataflow as r15: at iter t, buf[p^1] holds
//   h1(t-1) & h2(t-2); epi1 writes h1(t), epi2 writes h2(t-1) into buf[p].
__global__ __launch_bounds__(512, 1) void lstm_mfma(
    const int* __restrict__ tokens, const f32x4* __restrict__ E1f4,
    const uint4* __restrict__ B1f, const uint4* __restrict__ B2f,
    const float* __restrict__ b2, const float* __restrict__ Wd,
    const float* __restrict__ bd, float* __restrict__ out) {
    __shared__ uint4 AbufU[512];                  // 2 bufs x 256 uint4 = 8 KB
    __shared__ float red[64];
    f16* Abuf = (f16*)AbufU;

    const int tid  = threadIdx.x;
    const int w    = tid >> 6;                    // 0..7
    const bool isL1 = (w < 4);
    const int wl   = w & 3;                       // unit block 0..3
    const int lane = tid & 63;
    const int q    = lane >> 4;
    const int li   = lane & 15;
    const int u    = wl * 16 + li;                // this lane's unit (output col)
    const int row0 = blockIdx.x * 16;

    const uint4 z4 = {0u, 0u, 0u, 0u};
    AbufU[tid] = z4;                              // zero both buffers (512 thr)

    const float bdv = bd[0];

    // ---- L1 state ----
    uint4 b1f[4][2];
    int4  tokc[4], tokn[4];
    f32x4 e1buf[2][4];
    float c1[4] = {0.f, 0.f, 0.f, 0.f};
    // ---- L2 state ----
    uint4 b2f[4][4];
    float b2v[4];
    float c2[4] = {0.f, 0.f, 0.f, 0.f};
    float h2v[4] = {0.f, 0.f, 0.f, 0.f};
    float wdv = 0.f;

    if (isL1) {
#pragma unroll
        for (int g = 0; g < 4; ++g)
#pragma unroll
            for (int kt = 0; kt < 2; ++kt)
                b1f[g][kt] = B1f[((wl * 4 + g) * 2 + kt) * 64 + lane];
        // token window + depth-2 E1 prefetch (e1buf[t&1] holds step t's rows)
#pragma unroll
        for (int r = 0; r < 4; ++r) {
            tokc[r] = *(const int4*)(tokens + (size_t)(row0 + q * 4 + r) * SEQ);
            e1buf[0][r] = E1f4[(size_t)tokc[r].x * 64 + u];
            e1buf[1][r] = E1f4[(size_t)tokc[r].y * 64 + u];
        }
    } else {
#pragma unroll
        for (int g = 0; g < 4; ++g)
#pragma unroll
            for (int kt = 0; kt < 4; ++kt)
                b2f[g][kt] = B2f[((wl * 4 + g) * 4 + kt) * 64 + lane];
#pragma unroll
        for (int g = 0; g < 4; ++g)
            b2v[g] = ((g == 2) ? GSC : NSC) * b2[g * 64 + u];
        wdv = Wd[u];
    }

    // pipelined fragment registers (seeded 0: h1(-1)=0, h2(-2)=0)
    uint4 a1f0 = z4, a1f1 = z4, a2f0 = z4, a2f1 = z4;

    __syncthreads();                              // init barrier (full drain, once)

#pragma unroll 1
    for (int t4 = 0; t4 < SEQ / 4; ++t4) {
        if (isL1 && t4 < SEQ / 4 - 1) {
#pragma unroll
            for (int r = 0; r < 4; ++r)
                tokn[r] = *(const int4*)(tokens + (size_t)(row0 + q * 4 + r) * SEQ + (t4 + 1) * 4);
        }
#pragma unroll
        for (int s = 0; s < 4; ++s) {
            const int p = s & 1;                  // == t&1 (t4*4 is even)

            if (isL1) {
                // ---- L1: MFMA1(t): zs1 = e1(t) (C-init) + h1(t-1) @ U1s ----
                f32x4 acc[4];
#pragma unroll
                for (int g = 0; g < 4; ++g) {
#pragma unroll
                    for (int r = 0; r < 4; ++r) acc[g][r] = e1buf[p][r][g];
                }
#pragma unroll
                for (int g = 0; g < 4; ++g) acc[g] = mfma16(a1f0, b1f[g][0], acc[g]);
#pragma unroll
                for (int g = 0; g < 4; ++g) acc[g] = mfma16(a1f1, b1f[g][1], acc[g]);

                // epi1(t): h1(t) -> buf[p].h1 (tile-row m = 4q+r)
#pragma unroll
                for (int r = 0; r < 4; ++r) {
                    float h1 = lstm_epi(acc[0][r], acc[1][r], acc[2][r], acc[3][r], c1[r]);
                    Abuf[p * 2048 + ((u >> 3) * 16 + 4 * q + r) * 8 + (u & 7)] = (f16)h1;
                }

                // gather e1 for t+2 (pre-barrier; vmcnt stays outstanding)
                if (t4 * 4 + s + 2 < SEQ) {
#pragma unroll
                    for (int r = 0; r < 4; ++r) {
                        int tk = (s == 0) ? tokc[r].z : (s == 1) ? tokc[r].w
                               : (s == 2) ? tokn[r].x : tokn[r].y;
                        e1buf[p][r] = E1f4[(size_t)tk * 64 + u];
                    }
                }
            } else {
                // ---- L2: MFMA2(t-1): zs2 = b2s (C-init) + [h1(t-1)|h2(t-2)] @ [W2;U2]s ----
                // (at t=0 garbage that epi2 discards — frags are zero)
                f32x4 acc2[4];
#pragma unroll
                for (int g = 0; g < 4; ++g) {
                    acc2[g][0] = b2v[g]; acc2[g][1] = b2v[g];
                    acc2[g][2] = b2v[g]; acc2[g][3] = b2v[g];
                }
#pragma unroll
                for (int g = 0; g < 4; ++g) acc2[g] = mfma16(a1f0, b2f[g][0], acc2[g]);
#pragma unroll
                for (int g = 0; g < 4; ++g) acc2[g] = mfma16(a1f1, b2f[g][1], acc2[g]);
#pragma unroll
                for (int g = 0; g < 4; ++g) acc2[g] = mfma16(a2f0, b2f[g][2], acc2[g]);
#pragma unroll
                for (int g = 0; g < 4; ++g) acc2[g] = mfma16(a2f1, b2f[g][3], acc2[g]);

                // epi2(t-1): h2(t-1) -> buf[p].h2 — SKIP at t==0 (h2(-1)=0)
                if (t4 | s) {
#pragma unroll
                    for (int r = 0; r < 4; ++r) {
                        h2v[r] = lstm_epi(acc2[0][r], acc2[1][r], acc2[2][r], acc2[3][r], c2[r]);
                        Abuf[p * 2048 + 1024 + ((u >> 3) * 16 + 4 * q + r) * 8 + (u & 7)] = (f16)h2v[r];
                    }
                }
            }

            barrier_lds();                        // end-of-step; lgkm-only

            // ds_read next epoch's frags: h1(t), h2(t-1) — consumed NEXT iteration
            a1f0 = AbufU[p * 256 + lane];
            a1f1 = AbufU[p * 256 + 64 + lane];
            if (!isL1) {
                a2f0 = AbufU[p * 256 + 128 + lane];
                a2f1 = AbufU[p * 256 + 192 + lane];
            }
        }
        if (isL1) {
#pragma unroll
            for (int r = 0; r < 4; ++r) tokc[r] = tokn[r];
        }
    }

    // ---- tail (L2 waves): MFMA2(79) + epi2(79), then head partial sums ----
    if (!isL1) {
        f32x4 acc2[4];
#pragma unroll
        for (int g = 0; g < 4; ++g) {
            acc2[g][0] = b2v[g]; acc2[g][1] = b2v[g];
            acc2[g][2] = b2v[g]; acc2[g][3] = b2v[g];
        }
#pragma unroll
        for (int g = 0; g < 4; ++g) acc2[g] = mfma16(a1f0, b2f[g][0], acc2[g]);
#pragma unroll
        for (int g = 0; g < 4; ++g) acc2[g] = mfma16(a1f1, b2f[g][1], acc2[g]);
#pragma unroll
        for (int g = 0; g < 4; ++g) acc2[g] = mfma16(a2f0, b2f[g][2], acc2[g]);
#pragma unroll
        for (int g = 0; g < 4; ++g) acc2[g] = mfma16(a2f1, b2f[g][3], acc2[g]);
#pragma unroll
        for (int r = 0; r < 4; ++r)
            h2v[r] = lstm_epi(acc2[0][r], acc2[1][r], acc2[2][r], acc2[3][r], c2[r]);

        // head: out[row] = sigmoid(sum_u h2[row][u]*Wd[u] + bd)
#pragma unroll
        for (int r = 0; r < 4; ++r) {
            float pv = h2v[r] * wdv;
            pv += __shfl_xor(pv, 1, 64);
            pv += __shfl_xor(pv, 2, 64);
            pv += __shfl_xor(pv, 4, 64);
            pv += __shfl_xor(pv, 8, 64);
            if (li == 0) red[wl * 16 + q * 4 + r] = pv;
        }
    }
    __syncthreads();
    if (tid < 16) {
        float sum = red[tid] + red[16 + tid] + red[32 + tid] + red[48 + tid] + bdv;
        out[row0 + tid] = sigm_exact(sum);
    }
}

// ---------------- fallback (no workspace): round-1 monolithic ----------------
__device__ __forceinline__ float lane_bcast(float v, int j) {
    return __builtin_bit_cast(float, __builtin_amdgcn_readlane(__builtin_bit_cast(int, v), j));
}
__device__ __forceinline__ float sigm_f(float x)  { return 1.0f / (1.0f + __expf(-x)); }
__device__ __forceinline__ float tanh_f(float x)  { return 2.0f / (1.0f + __expf(-2.0f * x)) - 1.0f; }

__global__ __launch_bounds__(512) void lstm_fused_fallback(
    const int* __restrict__ tokens, const float* __restrict__ emb,
    const float* __restrict__ W1, const float* __restrict__ U1, const float* __restrict__ b1,
    const float* __restrict__ W2, const float* __restrict__ U2, const float* __restrict__ b2,
    const float* __restrict__ Wd, const float* __restrict__ bd, float* __restrict__ out) {
    const int lane = threadIdx.x & 63;
    const int wave = threadIdx.x >> 6;
    const int row0 = blockIdx.x * 16 + wave * 2;
    float bias1[4], bias2[4];
#pragma unroll
    for (int g = 0; g < 4; ++g) { bias1[g] = b1[g * 64 + lane]; bias2[g] = b2[g * 64 + lane]; }
    const float wd = Wd[lane]; const float bdv = bd[0];
    float h1[2] = {0.f, 0.f}, c1[2] = {0.f, 0.f}, h2[2] = {0.f, 0.f}, c2[2] = {0.f, 0.f};
#pragma unroll 1
    for (int t = 0; t < SEQ; ++t) {
        float acc[4][2];
#pragma unroll
        for (int g = 0; g < 4; ++g) { acc[g][0] = bias1[g]; acc[g][1] = bias1[g]; }
        int tokA = __builtin_amdgcn_readfirstlane(tokens[(row0 + 0) * SEQ + t]);
        int tokB = __builtin_amdgcn_readfirstlane(tokens[(row0 + 1) * SEQ + t]);
        const float4* xA = (const float4*)(emb + (size_t)tokA * EMB);
        const float4* xB = (const float4*)(emb + (size_t)tokB * EMB);
#pragma unroll 5
        for (int d4 = 0; d4 < EMB / 4; ++d4) {
            float4 a4 = xA[d4]; float4 b4 = xB[d4];
            float av[4] = {a4.x, a4.y, a4.z, a4.w}; float bv[4] = {b4.x, b4.y, b4.z, b4.w};
#pragma unroll
            for (int e = 0; e < 4; ++e) {
                const float* wrow = W1 + (d4 * 4 + e) * 256;
#pragma unroll
                for (int g = 0; g < 4; ++g) {
                    float wv = wrow[g * 64 + lane];
                    acc[g][0] += av[e] * wv; acc[g][1] += bv[e] * wv;
                }
            }
        }
#pragma unroll 4
        for (int j = 0; j < 64; ++j) {
            float ha = lane_bcast(h1[0], j), hb = lane_bcast(h1[1], j);
            const float* urow = U1 + j * 256;
#pragma unroll
            for (int g = 0; g < 4; ++g) {
                float wv = urow[g * 64 + lane];
                acc[g][0] += ha * wv; acc[g][1] += hb * wv;
            }
        }
#pragma unroll
        for (int r = 0; r < 2; ++r) {
            float ig = sigm_f(acc[0][r]), fg = sigm_f(acc[1][r]);
            float gg = tanh_f(acc[2][r]), og = sigm_f(acc[3][r]);
            c1[r] = fg * c1[r] + ig * gg; h1[r] = og * tanh_f(c1[r]);
        }
        float acc2[4][2];
#pragma unroll
        for (int g = 0; g < 4; ++g) { acc2[g][0] = bias2[g]; acc2[g][1] = bias2[g]; }
#pragma unroll 4
        for (int j = 0; j < 64; ++j) {
            float pa = lane_bcast(h1[0], j), pb = lane_bcast(h1[1], j);
            float qa = lane_bcast(h2[0], j), qb = lane_bcast(h2[1], j);
            const float* w2row = W2 + j * 256; const float* u2row = U2 + j * 256;
#pragma unroll
            for (int g = 0; g < 4; ++g) {
                float w2v = w2row[g * 64 + lane], u2v = u2row[g * 64 + lane];
                acc2[g][0] += pa * w2v + qa * u2v;
                acc2[g][1] += pb * w2v + qb * u2v;
            }
        }
#pragma unroll
        for (int r = 0; r < 2; ++r) {
            float ig = sigm_f(acc2[0][r]), fg = sigm_f(acc2[1][r]);
            float gg = tanh_f(acc2[2][r]), og = sigm_f(acc2[3][r]);
            c2[r] = fg * c2[r] + ig * gg; h2[r] = og * tanh_f(c2[r]);
        }
    }
#pragma unroll
    for (int r = 0; r < 2; ++r) {
        float p = h2[r] * wd;
#pragma unroll
        for (int off = 32; off > 0; off >>= 1) p += __shfl_down(p, off, 64);
        if (lane == 0) out[row0 + r] = sigm_f(p + bdv);
    }
}

extern "C" void kernel_launch(void* const* d_in, const int* in_sizes, int n_in,
                              void* d_out, int out_size, void* d_ws, size_t ws_size,
                              hipStream_t stream) {
    const int*   tokens = (const int*)  d_in[0];
    const float* emb    = (const float*)d_in[1];
    const float* W1     = (const float*)d_in[2];
    const float* U1     = (const float*)d_in[3];
    const float* b1     = (const float*)d_in[4];
    const float* W2     = (const float*)d_in[5];
    const float* U2     = (const float*)d_in[6];
    const float* b2     = (const float*)d_in[7];
    const float* Wd     = (const float*)d_in[8];
    const float* bd     = (const float*)d_in[9];
    float* out = (float*)d_out;

    if (ws_size < (size_t)WS_NEEDED) {
        lstm_fused_fallback<<<256, 512, 0, stream>>>(tokens, emb, W1, U1, b1, W2, U2, b2, Wd, bd, out);
        return;
    }

    char*  ws  = (char*)d_ws;
    float* E1f = (float*)(ws + WS_E1F_OFF);
    uint*  B1f = (uint*) (ws + WS_B1F_OFF);
    uint*  B2f = (uint*) (ws + WS_B2F_OFF);

    prep_e1  <<<NB_GEMM + 64, 256, 0, stream>>>(emb, W1, U1, b1, W2, U2, E1f, B1f, B2f);
    lstm_mfma<<<NGRID, 512, 0, stream>>>(tokens, (const f32x4*)E1f,
                                         (const uint4*)B1f, (const uint4*)B2f,
                                         b2, Wd, bd, out);
}